// Round 8
// baseline (130.490 us; speedup 1.0000x reference)
//
#include <hip/hip_runtime.h>
#include <cstddef>

// Problem constants (from reference)
constexpr int kC = 81;            // NUM_CLASSES + 1
constexpr int kNumBase = 60;      // NUM_CLASSES // 4 * 3
constexpr int kNumClasses = 80;
constexpr float kWNovel = 1.0f / 10.0f;   // 1/SHOT
constexpr float kWBase = kWNovel / 3.0f;
constexpr float kWNeg = 0.001f;
constexpr float kEpsDiff = 1e-3f;
constexpr float kMaxLog = 5.0f;
constexpr float kMaxLoss = 1.0f;
constexpr int kMinSamp = 2;
constexpr int kShadows = 8;       // global-accumulator striping factor

// 16-byte vector with 4-byte alignment: wide global loads from float-aligned
// addresses.
typedef float float4u __attribute__((ext_vector_type(4), aligned(4)));

// R6/R7 structure with 2-WAY GROUP INTERLEAVE: each wave owns exactly two
// 16-row groups (16384 groups / 8192 waves); instead of processing them
// sequentially (load->long dependent compute->load->compute), both groups'
// loads are issued back-to-back and the two independent compute streams are
// interleaved -- 2x memory-level parallelism at the head, 2x ILP on the
// exp/log/shuffle latency chains. Unstabilized softmax (N(0,1) inputs, exact
// to fp32 -- R7 absmax was 0.0).
//
// NOTE (R5 lesson): do NOT fuse the finalize into this kernel — the cold
// epilogue collapsed regalloc (VGPR 40->24), spilling x[21] (10x slowdown).
__global__ __launch_bounds__(256) void adl_main(
    const float* __restrict__ cls,
    const int* __restrict__ labels,
    const float* __restrict__ lw,
    float* __restrict__ gsum,
    int* __restrict__ gcnt,
    int n) {
  __shared__ float ssum[kC];
  __shared__ int scnt[kC];
  const int tid = threadIdx.x;
  if (tid < kC) { ssum[tid] = 0.0f; scnt[tid] = 0; }
  __syncthreads();

  const int lane = tid & 63;
  const int wave = tid >> 6;
  const int q = lane & 3;                  // quad index within row
  const int rsub = lane >> 2;              // row within 16-row group
  const int gw = blockIdx.x * (blockDim.x >> 6) + wave;
  const int nw = gridDim.x * (blockDim.x >> 6);
  const int ngroups = n >> 4;              // N divisible by 16
  const int c0 = (q < 3) ? q * 21 : 60;    // first column for this lane

  for (int g = gw; g < ngroups; g += 2 * nw) {
    const int gB = g + nw;
    const bool hasB = (gB < ngroups);
    const int rowA = (g << 4) + rsub;
    const int rowB = ((hasB ? gB : g) << 4) + rsub;  // safe addr if no B
    const float* rpA = cls + (size_t)rowA * kC;
    const float* rpB = cls + (size_t)rowB * kC;

    // ---- issue BOTH groups' loads back-to-back (2x MLP) ----
    float xa[21], xb[21];
    {
      const float* pA = rpA + c0;
      const float* pB = rpB + c0;
#pragma unroll
      for (int k = 0; k < 5; ++k) {
        float4u vA = *(const float4u*)(pA + 4 * k);
        float4u vB = *(const float4u*)(pB + 4 * k);
        xa[4 * k + 0] = vA.x; xa[4 * k + 1] = vA.y;
        xa[4 * k + 2] = vA.z; xa[4 * k + 3] = vA.w;
        xb[4 * k + 0] = vB.x; xb[4 * k + 1] = vB.y;
        xb[4 * k + 2] = vB.z; xb[4 * k + 3] = vB.w;
      }
      xa[20] = pA[20];
      xb[20] = pB[20];
    }
    const int labelA = labels[rowA];
    const int labelB = labels[rowB];
    const float lwA = lw[rowA];
    const float lwB = hasB ? lw[rowB] : 0.0f;   // lwB=0 kills B's update
    const float rawA = rpA[labelA];             // L1-hot gather
    const float rawB = rpB[labelB];

    // ---- exp + denom, both streams interleaved ----
    float sa = 0.0f, sb = 0.0f;
#pragma unroll
    for (int j = 0; j < 21; ++j) {
      xa[j] = __expf(xa[j]);
      xb[j] = __expf(xb[j]);
      const bool dup = (j < 3 && q == 3);
      sa += dup ? 0.0f : xa[j];
      sb += dup ? 0.0f : xb[j];
    }
    sa += __shfl_xor(sa, 1);
    sb += __shfl_xor(sb, 1);
    sa += __shfl_xor(sa, 2);
    sb += __shfl_xor(sb, 2);
    const float invA = 1.0f / sa;
    const float invB = 1.0f / sb;

    const float ptA = __expf(rawA) * invA;
    const float ptB = __expf(rawB) * invB;

    const float omA = fminf(fmaxf(1.0f - ptA, 1e-4f), 1.0f);
    const float omB = fminf(fmaxf(1.0f - ptB, 1e-4f), 1.0f);
    const float wA = omA * omA;
    const float wB = omB * omB;

    // ---- margin terms, both streams interleaved ----
    float ta = 0.0f, tb = 0.0f;
#pragma unroll
    for (int j = 0; j < 21; ++j) {
      const float dA = fminf(fmaxf(ptA - xa[j] * invA, kEpsDiff), 1.0f);
      const float dB = fminf(fmaxf(ptB - xb[j] * invB, kEpsDiff), 1.0f);
      const float trA = fminf(-__logf(dA), kMaxLog);
      const float trB = fminf(-__logf(dB), kMaxLog);
      const bool dup = (j < 3 && q == 3);
      ta += dup ? 0.0f : trA;
      tb += dup ? 0.0f : trB;
    }
    ta += __shfl_xor(ta, 1);
    tb += __shfl_xor(tb, 1);
    ta += __shfl_xor(ta, 2);
    tb += __shfl_xor(tb, 2);

    // True-column term is exactly 5 (clip(0,1e-3,1)=1e-3, -log(1e-3)=6.9>5),
    // so the sum over the C-1 'other' columns is (t - 5).
    if (q == 0) {
      if (lwA > 0.0f) {
        atomicAdd(&ssum[labelA], wA * (ta - kMaxLog));
        atomicAdd(&scnt[labelA], 1);
      }
      if (lwB > 0.0f) {
        atomicAdd(&ssum[labelB], wB * (tb - kMaxLog));
        atomicAdd(&scnt[labelB], 1);
      }
    }
  }

  __syncthreads();
  const int sh = blockIdx.x & (kShadows - 1);
  if (tid < kC && scnt[tid] != 0) {
    atomicAdd(&gsum[sh * kC + tid], ssum[tid]);
    atomicAdd(&gcnt[sh * kC + tid], scnt[tid]);
  }
}

// One wave: lane handles classes lane and lane+64 across the 8 shadow copies.
__global__ __launch_bounds__(64) void adl_final(const float* __restrict__ gsum,
                                                const int* __restrict__ gcnt,
                                                float* __restrict__ out) {
  const int lane = threadIdx.x;
  float sb = 0.0f, sn = 0.0f, sg = 0.0f;
  int nb = 0, nn = 0, ng = 0;
#pragma unroll
  for (int k = 0; k < 2; ++k) {
    const int c = lane + k * 64;
    if (c < kC) {
      float sm = 0.0f;
      int cnt = 0;
#pragma unroll
      for (int sh = 0; sh < kShadows; ++sh) {
        sm += gsum[sh * kC + c];
        cnt += gcnt[sh * kC + c];
      }
      if (c < kNumBase) {
        if (cnt >= kMinSamp) { sb += sm; nb += cnt; }
      } else if (c < kNumClasses) {
        if (cnt >= kMinSamp) { sn += sm; nn += cnt; }
      } else {
        sg += sm; ng += cnt;
      }
    }
  }
#pragma unroll
  for (int off = 32; off > 0; off >>= 1) {
    sb += __shfl_xor(sb, off);
    sn += __shfl_xor(sn, off);
    sg += __shfl_xor(sg, off);
    nb += __shfl_xor(nb, off);
    nn += __shfl_xor(nn, off);
    ng += __shfl_xor(ng, off);
  }
  if (lane == 0) {
    const double denom = (double)(kC - 1);
    double lb = (nb > 0) ? (double)sb / ((double)nb * denom) * (double)kWBase : 0.0;
    double ln = (nn > 0) ? (double)sn / ((double)nn * denom) * (double)kWNovel : 0.0;
    double lg = (ng > 0) ? (double)sg / ((double)ng * denom) * (double)kWNeg : 0.0;
    out[0] = (float)fmin(lb, (double)kMaxLoss);
    out[1] = (float)fmin(ln, (double)kMaxLoss);
    out[2] = (float)fmin(lg, (double)kMaxLoss);
  }
}

extern "C" void kernel_launch(void* const* d_in, const int* in_sizes, int n_in,
                              void* d_out, int out_size, void* d_ws, size_t ws_size,
                              hipStream_t stream) {
  const float* cls = (const float*)d_in[0];
  const int* labels = (const int*)d_in[1];
  const float* lw = (const float*)d_in[2];
  float* out = (float*)d_out;
  const int n = in_sizes[1];  // N, from labels

  float* gsum = (float*)d_ws;                                       // 8*81 floats
  int* gcnt = (int*)((char*)d_ws + kShadows * kC * sizeof(float));  // 8*81 ints

  // ws is re-poisoned to 0xAA before every call — zero our accumulators.
  hipMemsetAsync(d_ws, 0, kShadows * kC * (sizeof(float) + sizeof(int)), stream);

  // 2048 blocks x 256 threads = 8192 waves; 16384 groups -> each wave owns
  // exactly 2, processed interleaved in one straight-line pass.
  adl_main<<<2048, 256, 0, stream>>>(cls, labels, lw, gsum, gcnt, n);
  adl_final<<<1, 64, 0, stream>>>(gsum, gcnt, out);
}

// Round 9
// 127.769 us; speedup vs baseline: 1.0213x; 1.0213x over previous
//
#include <hip/hip_runtime.h>
#include <cstddef>

// Problem constants (from reference)
constexpr int kC = 81;            // NUM_CLASSES + 1
constexpr int kNumBase = 60;      // NUM_CLASSES // 4 * 3
constexpr int kNumClasses = 80;
constexpr float kWNovel = 1.0f / 10.0f;   // 1/SHOT
constexpr float kWBase = kWNovel / 3.0f;
constexpr float kWNeg = 0.001f;
constexpr float kEpsDiff = 1e-3f;
constexpr float kMaxLog = 5.0f;
constexpr float kMaxLoss = 1.0f;
constexpr int kMinSamp = 2;
constexpr int kShadows = 8;       // global-accumulator striping factor

// 16-byte vector with 4-byte alignment: lets us issue wide global loads
// from addresses that are only float-aligned.
typedef float float4u __attribute__((ext_vector_type(4), aligned(4)));

// FINAL: exact R6 configuration — best measured (128.15 us total; adl_main
// ~20 us of it, the other ~100 us is the harness's 324 MB ws re-poison fills
// at 6.6 TB/s plus input restore, outside kernel control).
//
// Session findings baked in:
//  - R5: do NOT fuse the finalize epilogue into adl_main — regalloc collapses
//    (VGPR 40->24), x[21] spills, 10x slowdown. Keep two kernels.
//  - R4: coalesced loads via wave-private LDS transpose do not beat the
//    direct scattered loads (the 5.4 KB/wave window is L1-resident).
//  - R7: removing softmax max-stabilization is numerically exact here but
//    performance-neutral (not chain-bound).
//  - R8: 2-way group interleave (2x MLP/ILP) is neutral (not latency-bound
//    in a way more in-flight work per wave can fix).
//
// Structure: each wave grid-strides over 16-row groups; 4 lanes cooperate
// per row. Lane quad q in {0,1,2} loads columns [21q, 21q+21); q=3 loads
// [60,81) (3 overlap columns masked out of the sums). All 21 values live in
// VGPRs; reductions are 2-step intra-quad shuffles. Per-class (sum,count) ->
// LDS histogram -> one of 8 global shadow copies (8x less atomic contention).
__global__ __launch_bounds__(256) void adl_main(
    const float* __restrict__ cls,
    const int* __restrict__ labels,
    const float* __restrict__ lw,
    float* __restrict__ gsum,
    int* __restrict__ gcnt,
    int n) {
  __shared__ float ssum[kC];
  __shared__ int scnt[kC];
  const int tid = threadIdx.x;
  if (tid < kC) { ssum[tid] = 0.0f; scnt[tid] = 0; }
  __syncthreads();

  const int lane = tid & 63;
  const int wave = tid >> 6;
  const int q = lane & 3;                  // quad index within row
  const int rsub = lane >> 2;              // row within 16-row group
  const int gw = blockIdx.x * (blockDim.x >> 6) + wave;
  const int nw = gridDim.x * (blockDim.x >> 6);
  const int ngroups = n >> 4;              // N divisible by 16
  const int c0 = (q < 3) ? q * 21 : 60;    // first column for this lane

  for (int g = gw; g < ngroups; g += nw) {
    const int row = (g << 4) + rsub;
    const float* rp = cls + (size_t)row * kC;

    // ---- load 21 columns: 5 x 16B vector loads (align 4) + 1 scalar ----
    float x[21];
    const float* p = rp + c0;
#pragma unroll
    for (int k = 0; k < 5; ++k) {
      float4u v = *(const float4u*)(p + 4 * k);
      x[4 * k + 0] = v.x; x[4 * k + 1] = v.y;
      x[4 * k + 2] = v.z; x[4 * k + 3] = v.w;
    }
    x[20] = p[20];

    // ---- softmax max (duplicated cols harmless for max) ----
    float m = x[0];
#pragma unroll
    for (int j = 1; j < 21; ++j) m = fmaxf(m, x[j]);
    m = fmaxf(m, __shfl_xor(m, 1));
    m = fmaxf(m, __shfl_xor(m, 2));

    // ---- exp + denom (mask the 3 duplicated cols on q==3) ----
    float s = 0.0f;
#pragma unroll
    for (int j = 0; j < 21; ++j) {
      x[j] = __expf(x[j] - m);
      s += (j < 3 && q == 3) ? 0.0f : x[j];
    }
    s += __shfl_xor(s, 1);
    s += __shfl_xor(s, 2);
    const float inv = 1.0f / s;

    const int label = labels[row];         // 4 dup lanes/row, L1-hot
    const float p_true = __expf(rp[label] - m) * inv;  // extra L1-hot load

    const float om = fminf(fmaxf(1.0f - p_true, 1e-4f), 1.0f);
    const float w = om * om;

    // ---- margin terms: min(-log(clip(p_true - p_c, 1e-3, 1)), 5) ----
    float t = 0.0f;
#pragma unroll
    for (int j = 0; j < 21; ++j) {
      const float d = fminf(fmaxf(p_true - x[j] * inv, kEpsDiff), 1.0f);
      const float term = fminf(-__logf(d), kMaxLog);
      t += (j < 3 && q == 3) ? 0.0f : term;
    }
    t += __shfl_xor(t, 1);
    t += __shfl_xor(t, 2);

    // True-column term is exactly 5 (clip(0,1e-3,1)=1e-3, -log(1e-3)=6.9>5),
    // so the sum over the C-1 'other' columns is (t - 5).
    if (q == 0) {
      if (lw[row] > 0.0f) {
        atomicAdd(&ssum[label], w * (t - kMaxLog));
        atomicAdd(&scnt[label], 1);
      }
    }
  }

  __syncthreads();
  const int sh = blockIdx.x & (kShadows - 1);
  if (tid < kC && scnt[tid] != 0) {
    atomicAdd(&gsum[sh * kC + tid], ssum[tid]);
    atomicAdd(&gcnt[sh * kC + tid], scnt[tid]);
  }
}

// One wave: lane handles classes lane and lane+64 across the 8 shadow copies.
__global__ __launch_bounds__(64) void adl_final(const float* __restrict__ gsum,
                                                const int* __restrict__ gcnt,
                                                float* __restrict__ out) {
  const int lane = threadIdx.x;
  float sb = 0.0f, sn = 0.0f, sg = 0.0f;
  int nb = 0, nn = 0, ng = 0;
#pragma unroll
  for (int k = 0; k < 2; ++k) {
    const int c = lane + k * 64;
    if (c < kC) {
      float sm = 0.0f;
      int cnt = 0;
#pragma unroll
      for (int sh = 0; sh < kShadows; ++sh) {
        sm += gsum[sh * kC + c];
        cnt += gcnt[sh * kC + c];
      }
      if (c < kNumBase) {
        if (cnt >= kMinSamp) { sb += sm; nb += cnt; }
      } else if (c < kNumClasses) {
        if (cnt >= kMinSamp) { sn += sm; nn += cnt; }
      } else {
        sg += sm; ng += cnt;
      }
    }
  }
#pragma unroll
  for (int off = 32; off > 0; off >>= 1) {
    sb += __shfl_xor(sb, off);
    sn += __shfl_xor(sn, off);
    sg += __shfl_xor(sg, off);
    nb += __shfl_xor(nb, off);
    nn += __shfl_xor(nn, off);
    ng += __shfl_xor(ng, off);
  }
  if (lane == 0) {
    const double denom = (double)(kC - 1);
    double lb = (nb > 0) ? (double)sb / ((double)nb * denom) * (double)kWBase : 0.0;
    double ln = (nn > 0) ? (double)sn / ((double)nn * denom) * (double)kWNovel : 0.0;
    double lg = (ng > 0) ? (double)sg / ((double)ng * denom) * (double)kWNeg : 0.0;
    out[0] = (float)fmin(lb, (double)kMaxLoss);
    out[1] = (float)fmin(ln, (double)kMaxLoss);
    out[2] = (float)fmin(lg, (double)kMaxLoss);
  }
}

extern "C" void kernel_launch(void* const* d_in, const int* in_sizes, int n_in,
                              void* d_out, int out_size, void* d_ws, size_t ws_size,
                              hipStream_t stream) {
  const float* cls = (const float*)d_in[0];
  const int* labels = (const int*)d_in[1];
  const float* lw = (const float*)d_in[2];
  float* out = (float*)d_out;
  const int n = in_sizes[1];  // N, from labels

  float* gsum = (float*)d_ws;                                       // 8*81 floats
  int* gcnt = (int*)((char*)d_ws + kShadows * kC * sizeof(float));  // 8*81 ints

  // ws is re-poisoned to 0xAA before every call — zero our accumulators.
  hipMemsetAsync(d_ws, 0, kShadows * kC * (sizeof(float) + sizeof(int)), stream);

  // 2048 blocks x 256 threads = 8192 waves; 16384 16-row groups -> 2/wave.
  // LDS 648 B, ~40 VGPR -> full 32 waves/CU occupancy, no hot-loop barriers.
  adl_main<<<2048, 256, 0, stream>>>(cls, labels, lw, gsum, gcnt, n);
  adl_final<<<1, 64, 0, stream>>>(gsum, gcnt, out);
}